// Round 1
// baseline (99.650 us; speedup 1.0000x reference)
//
#include <hip/hip_runtime.h>
#include <hip/hip_bf16.h>
#include <cstdint>

typedef __bf16 bf16_t;
typedef __attribute__((ext_vector_type(8))) __bf16 bf16x8;
typedef __attribute__((ext_vector_type(4))) float f32x4;

#define DIM 256
#define TINV 10.0f
#define BM 128
#define BN 128
#define BK 64

// Kernel 1: row-normalize y (f32) -> yn (bf16); zero rowsum accumulator.
__global__ void nt_normalize(const float* __restrict__ y, bf16_t* __restrict__ yn,
                             float* __restrict__ rowsum, int N) {
    int row = blockIdx.x;
    int tid = threadIdx.x;
    float v = y[(size_t)row * DIM + tid];
    float ss = v * v;
#pragma unroll
    for (int off = 32; off; off >>= 1) ss += __shfl_down(ss, off);
    __shared__ float part[4];
    if ((tid & 63) == 0) part[tid >> 6] = ss;
    __syncthreads();
    float tot = part[0] + part[1] + part[2] + part[3];
    float inv = 1.0f / fmaxf(sqrtf(tot), 1e-8f);
    yn[(size_t)row * DIM + tid] = (bf16_t)(v * inv);
    if (tid == 0) rowsum[row] = 0.0f;
}

// Kernel 2: fused sim-GEMM + exp + row-sum + pos capture.
// 128x128 tile, 4 waves (2x2), each wave owns 64x64 (4x4 frags of 16x16x32 bf16).
// LDS tiles XOR-swizzled (st-style, 16B chunks) via pre-swizzled global source
// (global_load_lds writes linearly: rule #21 both-sides-or-neither).
__launch_bounds__(256, 2)
__global__ void nt_gemm(const bf16_t* __restrict__ yn, float* __restrict__ rowsum,
                        float* __restrict__ posterm, int N) {
    __shared__ __align__(16) bf16_t As[BM][BK];
    __shared__ __align__(16) bf16_t Bs[BN][BK];
    const int ntiles = N / BN;
    int bx = blockIdx.x % ntiles;
    int by = blockIdx.x / ntiles;
    int r0 = by * BM, c0 = bx * BN;
    int tid = threadIdx.x;
    int wave = tid >> 6, lane = tid & 63;
    int wr = wave >> 1, wc = wave & 1;
    int l16 = lane & 15, lg = lane >> 4;

    f32x4 acc[4][4] = {};

    for (int k0 = 0; k0 < DIM; k0 += BK) {
        if (k0) __syncthreads();   // protect previous iter's LDS reads
        // Stage A,B tiles: 128x64 bf16 = 1024 16B-chunks each; 256 threads x 4 iters.
        // LDS chunk (row, cc) holds global chunk (row, cc ^ (row&7)).
#pragma unroll
        for (int it = 0; it < 4; ++it) {
            int cbase = it * 256 + wave * 64;     // wave-uniform chunk base
            int c = cbase + lane;                 // this lane's chunk
            int row = c >> 3, cc = c & 7;
            int gc = cc ^ (row & 7);
            const bf16_t* srcA = yn + (size_t)(r0 + row) * DIM + k0 + gc * 8;
            __builtin_amdgcn_global_load_lds(
                (const __attribute__((address_space(1))) uint32_t*)srcA,
                (__attribute__((address_space(3))) uint32_t*)((char*)&As[0][0] + cbase * 16),
                16, 0, 0);
            const bf16_t* srcB = yn + (size_t)(c0 + row) * DIM + k0 + gc * 8;
            __builtin_amdgcn_global_load_lds(
                (const __attribute__((address_space(1))) uint32_t*)srcB,
                (__attribute__((address_space(3))) uint32_t*)((char*)&Bs[0][0] + cbase * 16),
                16, 0, 0);
        }
        __syncthreads();   // drains vmcnt before any wave reads LDS

#pragma unroll
        for (int kk = 0; kk < 2; ++kk) {
            bf16x8 af[4], bfr[4];
#pragma unroll
            for (int m = 0; m < 4; ++m) {
                int row = wr * 64 + m * 16 + l16;
                int kc = kk * 4 + lg;
                af[m] = *(const bf16x8*)((const char*)&As[0][0] +
                                         row * (BK * 2) + ((kc ^ (row & 7)) * 16));
            }
#pragma unroll
            for (int n = 0; n < 4; ++n) {
                int row = wc * 64 + n * 16 + l16;
                int kc = kk * 4 + lg;
                bfr[n] = *(const bf16x8*)((const char*)&Bs[0][0] +
                                          row * (BK * 2) + ((kc ^ (row & 7)) * 16));
            }
#pragma unroll
            for (int m = 0; m < 4; ++m)
#pragma unroll
                for (int n = 0; n < 4; ++n)
                    acc[m][n] = __builtin_amdgcn_mfma_f32_16x16x32_bf16(
                        af[m], bfr[n], acc[m][n], 0, 0, 0);
        }
    }

    // Epilogue: e = exp(S/T); exclude diagonal; capture pos (col == row^1);
    // reduce 64 cols of this wave per output row, one atomicAdd per row.
    // C/D layout (m89): col = lane&15, row = (lane>>4)*4 + reg.
#pragma unroll
    for (int m = 0; m < 4; ++m) {
#pragma unroll
        for (int r = 0; r < 4; ++r) {
            int grow = r0 + wr * 64 + m * 16 + lg * 4 + r;
            float s = 0.0f;
#pragma unroll
            for (int n = 0; n < 4; ++n) {
                int gcol = c0 + wc * 64 + n * 16 + l16;
                float S = acc[m][n][r];
                float e = __expf(S * TINV);
                if (gcol == grow) e = 0.0f;                       // mask diagonal
                if (gcol == (grow ^ 1)) posterm[grow] = -S * TINV; // positive pair
                s += e;
            }
            // reduce across the 16 lanes sharing this grow (masks<16 stay in-group)
            s += __shfl_xor(s, 1);
            s += __shfl_xor(s, 2);
            s += __shfl_xor(s, 4);
            s += __shfl_xor(s, 8);
            if (l16 == 0) atomicAdd(&rowsum[grow], s);
        }
    }
}

// Kernel 3: loss = mean(posterm + log(rowsum))
__global__ void nt_reduce(const float* __restrict__ rowsum, const float* __restrict__ posterm,
                          float* __restrict__ out, int N) {
    __shared__ float part[16];
    int tid = threadIdx.x;
    float s = 0.0f;
    for (int i = tid; i < N; i += 1024)
        s += posterm[i] + logf(rowsum[i]);
#pragma unroll
    for (int off = 32; off; off >>= 1) s += __shfl_down(s, off);
    if ((tid & 63) == 0) part[tid >> 6] = s;
    __syncthreads();
    if (tid == 0) {
        float t = 0.0f;
#pragma unroll
        for (int w = 0; w < 16; ++w) t += part[w];
        out[0] = t / (float)N;
    }
}

extern "C" void kernel_launch(void* const* d_in, const int* in_sizes, int n_in,
                              void* d_out, int out_size, void* d_ws, size_t ws_size,
                              hipStream_t stream) {
    const float* y = (const float*)d_in[0];
    int N = in_sizes[0] / DIM;                 // 8192
    bf16_t* yn = (bf16_t*)d_ws;                // N*DIM bf16 = 4 MB
    float* rowsum = (float*)((char*)d_ws + (size_t)N * DIM * sizeof(bf16_t));
    float* posterm = rowsum + N;
    float* out = (float*)d_out;

    nt_normalize<<<N, 256, 0, stream>>>(y, yn, rowsum, N);
    int ntiles = N / BN;
    nt_gemm<<<ntiles * ntiles, 256, 0, stream>>>(yn, rowsum, posterm, N);
    nt_reduce<<<1, 1024, 0, stream>>>(rowsum, posterm, out, N);
}

// Round 2
// 66.656 us; speedup vs baseline: 1.4950x; 1.4950x over previous
//
#include <hip/hip_runtime.h>
#include <hip/hip_bf16.h>
#include <cstdint>

typedef __bf16 bf16_t;
typedef __attribute__((ext_vector_type(4))) __bf16 bf16x4;
typedef __attribute__((ext_vector_type(8))) __bf16 bf16x8;
typedef __attribute__((ext_vector_type(4))) float f32x4;

#define DIM 256
#define TINV 10.0f
#define BM 128
#define BN 128
#define BK 64

// Kernel 1: row-normalize y (f32) -> yn (bf16); zero rowsum accumulator.
// One row per wave, float4 per lane (64 lanes x 4 = 256 = DIM).
__global__ void nt_normalize(const float* __restrict__ y, bf16_t* __restrict__ yn,
                             float* __restrict__ rowsum, int N) {
    int tid = threadIdx.x;
    int wave = tid >> 6, lane = tid & 63;
    int row = blockIdx.x * 4 + wave;
    float4 v = ((const float4*)(y + (size_t)row * DIM))[lane];
    float ss = v.x * v.x + v.y * v.y + v.z * v.z + v.w * v.w;
#pragma unroll
    for (int off = 1; off < 64; off <<= 1) ss += __shfl_xor(ss, off);
    float inv = 1.0f / fmaxf(sqrtf(ss), 1e-8f);
    bf16x4 o;
    o[0] = (bf16_t)(v.x * inv);
    o[1] = (bf16_t)(v.y * inv);
    o[2] = (bf16_t)(v.z * inv);
    o[3] = (bf16_t)(v.w * inv);
    ((bf16x4*)(yn + (size_t)row * DIM))[lane] = o;
    if (lane == 0) rowsum[row] = 0.0f;
}

// Kernel 2: fused sim-GEMM + exp + row-sum + pos capture, SYMMETRIC:
// only tiles by <= bx are computed. Off-diagonal tiles add their exp-tile
// to rowsum[row] (col-reduce) AND rowsum[col] (row-reduce, e[r][c]==e[c][r]).
// Diagonal masking / positive-pair capture happen only in by==bx blocks.
// 128x128 tile, 4 waves (2x2), each wave owns 64x64 (4x4 frags of 16x16x32 bf16).
// LDS tiles XOR-swizzled via pre-swizzled global source (rule #21).
__launch_bounds__(256, 2)
__global__ void nt_gemm(const bf16_t* __restrict__ yn, float* __restrict__ rowsum,
                        float* __restrict__ posterm, int N) {
    const int ntiles = N / BN;
    int bx = blockIdx.x % ntiles;
    int by = blockIdx.x / ntiles;
    if (by > bx) return;                       // block-uniform: symmetric half skipped
    __shared__ __align__(16) bf16_t As[BM][BK];
    __shared__ __align__(16) bf16_t Bs[BN][BK];
    int r0 = by * BM, c0 = bx * BN;
    int tid = threadIdx.x;
    int wave = tid >> 6, lane = tid & 63;
    int wr = wave >> 1, wc = wave & 1;
    int l16 = lane & 15, lg = lane >> 4;

    f32x4 acc[4][4] = {};

    for (int k0 = 0; k0 < DIM; k0 += BK) {
        if (k0) __syncthreads();   // protect previous iter's LDS reads
        // Stage A,B tiles: 128x64 bf16 = 1024 16B-chunks each; 256 threads x 4 iters.
        // LDS chunk (row, cc) holds global chunk (row, cc ^ (row&7)).
#pragma unroll
        for (int it = 0; it < 4; ++it) {
            int cbase = it * 256 + wave * 64;     // wave-uniform chunk base
            int c = cbase + lane;                 // this lane's chunk
            int row = c >> 3, cc = c & 7;
            int gc = cc ^ (row & 7);
            const bf16_t* srcA = yn + (size_t)(r0 + row) * DIM + k0 + gc * 8;
            __builtin_amdgcn_global_load_lds(
                (const __attribute__((address_space(1))) uint32_t*)srcA,
                (__attribute__((address_space(3))) uint32_t*)((char*)&As[0][0] + cbase * 16),
                16, 0, 0);
            const bf16_t* srcB = yn + (size_t)(c0 + row) * DIM + k0 + gc * 8;
            __builtin_amdgcn_global_load_lds(
                (const __attribute__((address_space(1))) uint32_t*)srcB,
                (__attribute__((address_space(3))) uint32_t*)((char*)&Bs[0][0] + cbase * 16),
                16, 0, 0);
        }
        __syncthreads();   // drains vmcnt before any wave reads LDS

#pragma unroll
        for (int kk = 0; kk < 2; ++kk) {
            bf16x8 af[4], bfr[4];
#pragma unroll
            for (int m = 0; m < 4; ++m) {
                int row = wr * 64 + m * 16 + l16;
                int kc = kk * 4 + lg;
                af[m] = *(const bf16x8*)((const char*)&As[0][0] +
                                         row * (BK * 2) + ((kc ^ (row & 7)) * 16));
            }
#pragma unroll
            for (int n = 0; n < 4; ++n) {
                int row = wc * 64 + n * 16 + l16;
                int kc = kk * 4 + lg;
                bfr[n] = *(const bf16x8*)((const char*)&Bs[0][0] +
                                          row * (BK * 2) + ((kc ^ (row & 7)) * 16));
            }
#pragma unroll
            for (int m = 0; m < 4; ++m)
#pragma unroll
                for (int n = 0; n < 4; ++n)
                    acc[m][n] = __builtin_amdgcn_mfma_f32_16x16x32_bf16(
                        af[m], bfr[n], acc[m][n], 0, 0, 0);
        }
    }

    // Epilogue. C/D layout (m89): col = lane&15, row = (lane>>4)*4 + reg.
    if (by == bx) {
        // Diagonal tile: full 128x128 computed (it is its own transpose).
        // Mask diagonal, capture pos pair, row-sum only.
#pragma unroll
        for (int m = 0; m < 4; ++m) {
#pragma unroll
            for (int r = 0; r < 4; ++r) {
                int grow = r0 + wr * 64 + m * 16 + lg * 4 + r;
                float s = 0.0f;
#pragma unroll
                for (int n = 0; n < 4; ++n) {
                    int gcol = c0 + wc * 64 + n * 16 + l16;
                    float S = acc[m][n][r];
                    float e = __expf(S * TINV);
                    if (gcol == grow) e = 0.0f;                        // mask diagonal
                    if (gcol == (grow ^ 1)) posterm[grow] = -S * TINV; // positive pair
                    s += e;
                }
                s += __shfl_xor(s, 1);
                s += __shfl_xor(s, 2);
                s += __shfl_xor(s, 4);
                s += __shfl_xor(s, 8);
                if (l16 == 0) atomicAdd(&rowsum[grow], s);
            }
        }
    } else {
        // Off-diagonal tile (by < bx): no diagonal, no pos pair.
        // Row sums for rows r0.., col sums (== row sums of transposed half) for cols c0..
        float colacc[4] = {0.0f, 0.0f, 0.0f, 0.0f};
#pragma unroll
        for (int m = 0; m < 4; ++m) {
#pragma unroll
            for (int r = 0; r < 4; ++r) {
                int grow = r0 + wr * 64 + m * 16 + lg * 4 + r;
                float s = 0.0f;
#pragma unroll
                for (int n = 0; n < 4; ++n) {
                    float e = __expf(acc[m][n][r] * TINV);
                    s += e;
                    colacc[n] += e;
                }
                s += __shfl_xor(s, 1);
                s += __shfl_xor(s, 2);
                s += __shfl_xor(s, 4);
                s += __shfl_xor(s, 8);
                if (l16 == 0) atomicAdd(&rowsum[grow], s);
            }
        }
        // colacc[n] holds partial sum over this lane's 16 rows for col n*16+l16;
        // lanes sharing l16 (lg=0..3) hold the remaining rows -> reduce across lg.
#pragma unroll
        for (int n = 0; n < 4; ++n) {
            colacc[n] += __shfl_xor(colacc[n], 16);
            colacc[n] += __shfl_xor(colacc[n], 32);
        }
        if (lane < 16) {
#pragma unroll
            for (int n = 0; n < 4; ++n)
                atomicAdd(&rowsum[c0 + wc * 64 + n * 16 + l16], colacc[n]);
        }
    }
}

// Kernel 3: loss = mean(posterm + log(rowsum))
__global__ void nt_reduce(const float* __restrict__ rowsum, const float* __restrict__ posterm,
                          float* __restrict__ out, int N) {
    __shared__ float part[16];
    int tid = threadIdx.x;
    float s = 0.0f;
    for (int i = tid; i < N; i += 1024)
        s += posterm[i] + logf(rowsum[i]);
#pragma unroll
    for (int off = 32; off; off >>= 1) s += __shfl_down(s, off);
    if ((tid & 63) == 0) part[tid >> 6] = s;
    __syncthreads();
    if (tid == 0) {
        float t = 0.0f;
#pragma unroll
        for (int w = 0; w < 16; ++w) t += part[w];
        out[0] = t / (float)N;
    }
}

extern "C" void kernel_launch(void* const* d_in, const int* in_sizes, int n_in,
                              void* d_out, int out_size, void* d_ws, size_t ws_size,
                              hipStream_t stream) {
    const float* y = (const float*)d_in[0];
    int N = in_sizes[0] / DIM;                 // 8192
    bf16_t* yn = (bf16_t*)d_ws;                // N*DIM bf16 = 4 MB
    float* rowsum = (float*)((char*)d_ws + (size_t)N * DIM * sizeof(bf16_t));
    float* posterm = rowsum + N;
    float* out = (float*)d_out;

    nt_normalize<<<N / 4, 256, 0, stream>>>(y, yn, rowsum, N);
    int ntiles = N / BN;
    nt_gemm<<<ntiles * ntiles, 256, 0, stream>>>(yn, rowsum, posterm, N);
    nt_reduce<<<1, 1024, 0, stream>>>(rowsum, posterm, out, N);
}